// Round 4
// baseline (113.309 us; speedup 1.0000x reference)
//
#include <hip/hip_runtime.h>
#include <hip/hip_bf16.h>

// LIF recurrence: v = tau*v + (1-tau)*x_t ; s = (v > vth) ; v -= s (vth=1, reset=0)
// B=64, T=256, U=1024 fp32. Chains independent over (b,u), serial in t.
//
// R3 post-mortem: depth 16->32 neutral (~26.8us kernel, 3.9 TB/s) => not
// latency-depth-bound. Suspects: (a) non-temporal stores retire at HBM
// latency and share the vmcnt queue with loads -> every load-use waitcnt
// also drains slow nt stores; (b) 4B/lane dword VMEM ops at 2/element.
// R4: drop nt (128MB working set fits 256MB LLC; normal stores retire in
// L2), and go float2-per-thread: 2 chains/thread, 8B/lane, half the VMEM
// instructions. 32768 threads = 512 waves = 2 waves/CU; depth-16 float2
// rotating pipeline = 16KB/CU in flight (~3x Little's-law need).
//
// Bit-exactness vs numpy fp32: non-fused __fmul_rn/__fadd_rn so the spike
// compare (v > 1.0f) sees identical rounding to the reference.

constexpr int kB = 64;
constexpr int kT = 256;
constexpr int kU = 1024;
constexpr int kU2 = kU / 2;         // float2 columns per row
constexpr int kD = 16;              // pipeline depth (float2 loads in flight)

__global__ __launch_bounds__(128)
void lif_kernel(const float2* __restrict__ x, float2* __restrict__ out) {
    const int idx = blockIdx.x * blockDim.x + threadIdx.x;   // over B*U/2
    const int b  = idx >> 9;              // / kU2
    const int u2 = idx & (kU2 - 1);       // % kU2

    const size_t base = (size_t)b * kT * kU2 + u2;           // in float2 units
    const float2* __restrict__ xp = x + base;
    float2* __restrict__ op = out + base;

    float2 buf[kD];
#pragma unroll
    for (int j = 0; j < kD; ++j)
        buf[j] = xp[(size_t)j * kU2];

    float v0 = 0.0f, v1 = 0.0f;
    for (int c = 0; c < kT / kD - 1; ++c) {
        const int t0 = c * kD;
#pragma unroll
        for (int j = 0; j < kD; ++j) {
            const float2 xt = buf[j];                         // issued kD ago
            buf[j] = xp[(size_t)(t0 + kD + j) * kU2];         // refill slot
            v0 = __fadd_rn(__fmul_rn(0.25f, v0), __fmul_rn(0.75f, xt.x));
            v1 = __fadd_rn(__fmul_rn(0.25f, v1), __fmul_rn(0.75f, xt.y));
            const float s0 = (v0 > 1.0f) ? 1.0f : 0.0f;
            const float s1 = (v1 > 1.0f) ? 1.0f : 0.0f;
            v0 = __fsub_rn(v0, s0);
            v1 = __fsub_rn(v1, s1);
            op[(size_t)(t0 + j) * kU2] = make_float2(s0, s1); // normal store
        }
    }
    const int t0 = kT - kD;
#pragma unroll
    for (int j = 0; j < kD; ++j) {
        const float2 xt = buf[j];
        v0 = __fadd_rn(__fmul_rn(0.25f, v0), __fmul_rn(0.75f, xt.x));
        v1 = __fadd_rn(__fmul_rn(0.25f, v1), __fmul_rn(0.75f, xt.y));
        const float s0 = (v0 > 1.0f) ? 1.0f : 0.0f;
        const float s1 = (v1 > 1.0f) ? 1.0f : 0.0f;
        v0 = __fsub_rn(v0, s0);
        v1 = __fsub_rn(v1, s1);
        op[(size_t)(t0 + j) * kU2] = make_float2(s0, s1);
    }
}

extern "C" void kernel_launch(void* const* d_in, const int* in_sizes, int n_in,
                              void* d_out, int out_size, void* d_ws, size_t ws_size,
                              hipStream_t stream) {
    const float2* x = (const float2*)d_in[0];
    float2* out = (float2*)d_out;

    const int nthreads = kB * kU / 2;      // 32768 float2 chains
    const int block = 128;                 // 2 waves/block
    const int grid = nthreads / block;     // 256 blocks -> 1 block/CU, 2 waves/CU
    lif_kernel<<<grid, block, 0, stream>>>(x, out);
}

// Round 6
// 113.145 us; speedup vs baseline: 1.0014x; 1.0014x over previous
//
#include <hip/hip_runtime.h>
#include <hip/hip_bf16.h>

// LIF recurrence: v = tau*v + (1-tau)*x_t ; s = (v > vth) ; v -= s (vth=1, reset=0)
// B=64, T=256, U=1024 fp32. One thread per (b,u) chain; coalesced across u.
//
// R2-R4 post-mortems: depth (16 vs 32) neutral, width (dword vs x2) neutral-to-
// worse, nt-vs-normal neutral => plateau ~26us (~3.9 TB/s HBM) is NOT latency-
// depth or access-width. Remaining model: in-order vmcnt retirement couples the
// interleaved store stream to every load-wait (1 store between every 2 loads ->
// load consumption throttled by store-ack rate; pure-write fill kernel hits
// 6.4 TB/s with a homogeneous queue).
//
// R5 (fixed compile: native ext_vector float4 for nontemporal builtin):
// decouple streams. Accumulate 16 t of spikes in a PER-WAVE LDS tile
// (intra-wave, zero barriers), transpose via LDS, emit 4 wide (float4) nt
// stores per 16 t instead of 16 interleaved dword stores. Load prefetch stays
// 16 deep (R2's proven depth). Store queue entries per group: 16 -> 4, issued
// as a burst with a full group of slack to retire.
//
// Bit-exactness vs numpy fp32: non-fused __fmul_rn/__fadd_rn so the spike
// compare (v > 1.0f) sees identical rounding to the reference.

typedef float vfloat4 __attribute__((ext_vector_type(4)));

constexpr int kB = 64;
constexpr int kT = 256;
constexpr int kU = 1024;
constexpr int kG = 16;              // t-group size (also load prefetch depth)
constexpr int kPad = 72;            // LDS row stride in floats (64 + 8 pad)

__global__ __launch_bounds__(256)
void lif_kernel(const float* __restrict__ x, float* __restrict__ out) {
    const int idx  = blockIdx.x * blockDim.x + threadIdx.x;  // over B*U
    const int b    = idx >> 10;             // / kU
    const int u    = idx & (kU - 1);        // % kU
    const int lane = threadIdx.x & 63;
    const int wav  = threadIdx.x >> 6;

    const size_t base = (size_t)b * kT * kU + u;
    const float* __restrict__ xp = x + base;
    const int ubase = u - lane;             // first u of this wave (64-aligned)
    const size_t obase = (size_t)b * kT * kU + ubase;

    // per-wave 16t x 64u spike tile, padded row stride (no cross-wave sharing,
    // so intra-wave ds_write -> ds_read needs no barrier)
    __shared__ float tile[4][kG][kPad];
    float (*T)[kPad] = tile[wav];

    float buf[kG], nbuf[kG];
#pragma unroll
    for (int j = 0; j < kG; ++j)
        buf[j] = xp[(size_t)j * kU];

    float v = 0.0f;
    for (int g = 0; g < kT / kG; ++g) {
        const int t0 = g * kG;
        const bool more = (g + 1 < kT / kG);
        if (more) {
#pragma unroll
            for (int j = 0; j < kG; ++j)
                nbuf[j] = xp[(size_t)(t0 + kG + j) * kU];   // prefetch next group
        }
        // compute 16 timesteps; spikes go to LDS (banks: lane mod 32, 2-way, free)
#pragma unroll
        for (int j = 0; j < kG; ++j) {
            const float a  = __fmul_rn(0.25f, v);
            const float cc = __fmul_rn(0.75f, buf[j]);
            v = __fadd_rn(a, cc);
            const float s = (v > 1.0f) ? 1.0f : 0.0f;
            v = __fsub_rn(v, s);
            T[j][lane] = s;
        }
        // intra-wave transpose read + 4 wide nt stores for this group.
        // pass p: lane -> t-row tt = lane&15, float4 group grp = (lane>>4)+4p.
        // Store: 16 contiguous 64B segments per instruction (full lines).
#pragma unroll
        for (int p = 0; p < 4; ++p) {
            const int tt  = lane & 15;
            const int grp = (lane >> 4) + 4 * p;
            const vfloat4 w = *(const vfloat4*)&T[tt][grp * 4];
            __builtin_nontemporal_store(
                w, (vfloat4*)&out[obase + (size_t)(t0 + tt) * kU + grp * 4]);
        }
        if (more) {
#pragma unroll
            for (int j = 0; j < kG; ++j)
                buf[j] = nbuf[j];
        }
    }
}

extern "C" void kernel_launch(void* const* d_in, const int* in_sizes, int n_in,
                              void* d_out, int out_size, void* d_ws, size_t ws_size,
                              hipStream_t stream) {
    const float* x = (const float*)d_in[0];
    float* out = (float*)d_out;

    const int nthreads = kB * kU;          // 65536 chains
    const int block = 256;
    const int grid = nthreads / block;     // 256 blocks -> 1 block/CU, 4 waves/CU
    lif_kernel<<<grid, block, 0, stream>>>(x, out);
}